// Round 4
// baseline (291.196 us; speedup 1.0000x reference)
//
#include <hip/hip_runtime.h>
#include <math.h>

// Problem constants (E zonotope rows, content = C*H*W)
#define EROWS 64
#define NCOL  8192                   // 8*32*32
#define TAIL_OFF (EROWS * NCOL)      // floats before tail
#define ROW_F4  (NCOL / 4)           // float4 per row (2048)
#define BODY_F4 ((EROWS - 1) * ROW_F4)   // 63*2048 = 129024 float4 in body
#define BODY_BLOCKS (BODY_F4 / 256)      // 504 blocks, 1 f4/thread
#define TAIL_BLOCKS NCOL                 // 1 row per block, 8 f4/thread

// Native vector type (HIP float4 is a class; nontemporal builtin rejects it)
typedef float vf4 __attribute__((ext_vector_type(4)));
typedef int   vi4 __attribute__((ext_vector_type(4)));

// ws layout (bytes): val@0, flag@32768, colof@65536, tailval@98304,
// count@131072, scale@135168 (16B aligned for float4 loads)
#define WS_VAL(ws)     ((float*)(ws))
#define WS_FLAG(ws)    ((int*)((char*)(ws) + 32768))
#define WS_COLOF(ws)   ((int*)((char*)(ws) + 65536))
#define WS_TAILVAL(ws) ((float*)((char*)(ws) + 98304))
#define WS_COUNT(ws)   ((int*)((char*)(ws) + 131072))
#define WS_SCALE(ws)   ((float*)((char*)(ws) + 135168))

// Kernel A: per-column stats. Reads x once (2 MB), writes head row + small
// per-column arrays. Math op-order identical to the verified R0/R1 kernel.
__global__ void colstats_kernel(const float* __restrict__ x,
                                float* __restrict__ out,
                                float* __restrict__ val,
                                int* __restrict__ flag,
                                float* __restrict__ scale) {
    int k = blockIdx.x * blockDim.x + threadIdx.x;
    if (k >= NCOL) return;

    float err = 0.f;
    for (int e = 1; e < EROWS; ++e)
        err += fabsf(x[e * NCOL + k]);

    float x0    = x[k];
    float upper = x0 + err;
    float lower = x0 - err;

    float cross  = (lower * upper < 0.f) ? 1.f : 0.f;
    float nonneg = (lower >= 0.f) ? 1.f : 0.f;

    float lam = nonneg + cross * upper / (upper - lower);
    if (isnan(lam)) lam = 0.5f;

    float delta = fmaxf(-lam * lower, (1.f - lam) * upper);

    out[k]   = (delta * 0.5f + lam * x0) * cross + x0 * nonneg;   // head row
    val[k]   = delta * 0.5f;
    flag[k]  = (cross > 0.f) ? 1 : 0;
    scale[k] = lam * cross + nonneg;
}

// Kernel B: 256-thread stream-compaction scan (wave-64 shuffle scan, 2
// barriers). Emits inverse map: colof[r] = column of r-th crossing,
// tailval[r] = val there, count = total crossings.
__global__ void scan_kernel(const float* __restrict__ val,
                            const int* __restrict__ flag,
                            int* __restrict__ colof,
                            float* __restrict__ tailval,
                            int* __restrict__ count) {
    const int t    = threadIdx.x;        // 256 threads
    const int lane = t & 63;
    const int wave = t >> 6;             // 4 waves
    const int PER  = NCOL / 256;         // 32 consecutive columns per thread

    int f[PER];
    int mysum = 0;
    const vi4* fp = (const vi4*)(flag + t * PER);
    for (int j = 0; j < PER / 4; ++j) {
        vi4 v = fp[j];
        f[4*j+0] = v.x; f[4*j+1] = v.y; f[4*j+2] = v.z; f[4*j+3] = v.w;
        mysum += v.x + v.y + v.z + v.w;
    }

    // wave-inclusive scan of per-thread sums
    int s = mysum;
    for (int off = 1; off < 64; off <<= 1) {
        int v = __shfl_up(s, off);
        if (lane >= off) s += v;
    }

    __shared__ int wsum[4];
    if (lane == 63) wsum[wave] = s;
    __syncthreads();
    int wbase = 0;
    for (int w = 0; w < wave; ++w) wbase += wsum[w];

    int running = wbase + s - mysum;     // exclusive prefix for this thread

    for (int j = 0; j < PER; ++j) {
        int k = t * PER + j;
        if (f[j]) {
            colof[running]   = k;
            tailval[running] = val[k];
            ++running;
        }
    }
    if (t == 255) *count = wsum[0] + wsum[1] + wsum[2] + wsum[3];
}

// Kernel C: fused body + tail writer (single pass over all remaining output).
// Body blocks: out[e][k] = x[e][k] * scale[k], float4.
// Tail blocks: one 8192-float row per block; zeros except colof[row].
__global__ void write_kernel(const float* __restrict__ x,
                             const float* __restrict__ scale,
                             const int* __restrict__ colof,
                             const float* __restrict__ tailval,
                             const int* __restrict__ count,
                             float* __restrict__ out) {
    const int tid = threadIdx.x;

    if (blockIdx.x < BODY_BLOCKS) {
        int b = blockIdx.x * 256 + tid;          // f4 index in body [0,129024)
        int j = b & (ROW_F4 - 1);                // f4 within row
        int e = 1 + (b >> 11);                   // error-term row 1..63
        vf4 xv = ((const vf4*)x)[e * ROW_F4 + j];
        vf4 sv = ((const vf4*)scale)[j];
        ((vf4*)out)[e * ROW_F4 + j] = xv * sv;
    } else {
        int r   = blockIdx.x - BODY_BLOCKS;      // tail row [0,8192)
        int cnt = *count;
        int   col = (r < cnt) ? colof[r]   : -1; // ws is poisoned: guard
        float tv  = (r < cnt) ? tailval[r] : 0.f;

        vf4* rowp = (vf4*)out + (TAIL_OFF / 4) + (size_t)r * ROW_F4;
        #pragma unroll
        for (int i = 0; i < ROW_F4 / 256; ++i) { // 8 f4 per thread
            int j  = i * 256 + tid;
            int c0 = j << 2;
            vf4 v;
            v.x = (col == c0 + 0) ? tv : 0.f;
            v.y = (col == c0 + 1) ? tv : 0.f;
            v.z = (col == c0 + 2) ? tv : 0.f;
            v.w = (col == c0 + 3) ? tv : 0.f;
            __builtin_nontemporal_store(v, rowp + j);
        }
    }
}

extern "C" void kernel_launch(void* const* d_in, const int* in_sizes, int n_in,
                              void* d_out, int out_size, void* d_ws, size_t ws_size,
                              hipStream_t stream) {
    const float* x = (const float*)d_in[0];
    float* out = (float*)d_out;

    colstats_kernel<<<NCOL / 256, 256, 0, stream>>>(x, out, WS_VAL(d_ws),
                                                    WS_FLAG(d_ws), WS_SCALE(d_ws));
    scan_kernel<<<1, 256, 0, stream>>>(WS_VAL(d_ws), WS_FLAG(d_ws),
                                       WS_COLOF(d_ws), WS_TAILVAL(d_ws), WS_COUNT(d_ws));
    write_kernel<<<BODY_BLOCKS + TAIL_BLOCKS, 256, 0, stream>>>(
        x, WS_SCALE(d_ws), WS_COLOF(d_ws), WS_TAILVAL(d_ws), WS_COUNT(d_ws), out);
}

// Round 5
// 277.955 us; speedup vs baseline: 1.0476x; 1.0476x over previous
//
#include <hip/hip_runtime.h>
#include <math.h>

// Problem constants (E zonotope rows, content = C*H*W)
#define EROWS 64
#define NCOL  8192                   // 8*32*32
#define TAIL_OFF (EROWS * NCOL)      // floats before tail
#define TAIL_F4  (NCOL * NCOL / 4)   // 16,777,216 float4 in tail

#define STAT_BLOCKS 256              // 32 columns per stats block
#define FILL_F4_PER_BLOCK 4096       // 256 thr x 16 f4 = 64 KiB per block
#define FILL_BLOCKS (TAIL_F4 / FILL_F4_PER_BLOCK)   // 4096

// Native vector types
typedef float vf4 __attribute__((ext_vector_type(4)));
typedef int   vi4 __attribute__((ext_vector_type(4)));

// ws layout (bytes): val@0, flag@32768, colof@65536, tailval@98304, count@131072
#define WS_VAL(ws)     ((float*)(ws))
#define WS_FLAG(ws)    ((int*)((char*)(ws) + 32768))
#define WS_COLOF(ws)   ((int*)((char*)(ws) + 65536))
#define WS_TAILVAL(ws) ((float*)((char*)(ws) + 98304))
#define WS_COUNT(ws)   ((int*)((char*)(ws) + 131072))

// Kernel 1 (fused): stats blocks [0,256) + tail-zero fill blocks [256,4352).
// Stats block: 32 columns; threads (c = tid&31, eg = tid>>5) split the
// 63-row |x| reduction 8 ways (LDS combine), keep x values in regs, then
// write head row + scaled body rows. The 2 MiB of stats/body work hides
// under the 256 MiB fill.
__global__ void fused_kernel(const float* __restrict__ x,
                             float* __restrict__ out,
                             float* __restrict__ val,
                             int* __restrict__ flag) {
    const int tid = threadIdx.x;

    if (blockIdx.x >= STAT_BLOCKS) {
        // ---- tail zero fill: contiguous 64 KiB per block, plain f4 stores
        vf4 z; z.x = 0.f; z.y = 0.f; z.z = 0.f; z.w = 0.f;
        vf4* base = (vf4*)out + (TAIL_OFF / 4)
                  + (size_t)(blockIdx.x - STAT_BLOCKS) * FILL_F4_PER_BLOCK;
        #pragma unroll
        for (int i = 0; i < 16; ++i)
            base[i * 256 + tid] = z;
        return;
    }

    // ---- stats + body for 32 columns
    __shared__ float part[256];   // partial |x| sums, [eg][c]
    __shared__ float sc[32];      // per-column scale

    const int c   = tid & 31;
    const int eg  = tid >> 5;                 // 0..7
    const int col = blockIdx.x * 32 + c;

    float xv[8];
    int   ev[8];
    int   n = 0;
    float s = 0.f;
    #pragma unroll
    for (int j = 0; j < 8; ++j) {
        int e = eg + 8 * j;
        if (e == 0) continue;                 // row 0 is the center
        float v = x[e * NCOL + col];
        xv[n] = v; ev[n] = e; ++n;
        s += fabsf(v);
    }
    part[eg * 32 + c] = s;
    __syncthreads();

    if (tid < 32) {
        float err = 0.f;
        #pragma unroll
        for (int g = 0; g < 8; ++g)
            err += part[g * 32 + tid];

        int   k  = blockIdx.x * 32 + tid;
        float x0 = x[k];
        float upper = x0 + err;
        float lower = x0 - err;

        float cross  = (lower * upper < 0.f) ? 1.f : 0.f;
        float nonneg = (lower >= 0.f) ? 1.f : 0.f;

        float lam = nonneg + cross * upper / (upper - lower);
        if (isnan(lam)) lam = 0.5f;

        float delta = fmaxf(-lam * lower, (1.f - lam) * upper);

        out[k]   = (delta * 0.5f + lam * x0) * cross + x0 * nonneg;  // head
        val[k]   = delta * 0.5f;
        flag[k]  = (cross > 0.f) ? 1 : 0;
        sc[tid]  = lam * cross + nonneg;
    }
    __syncthreads();

    float scl = sc[c];
    #pragma unroll
    for (int i = 0; i < 8; ++i) {
        if (i < n)
            out[ev[i] * NCOL + col] = xv[i] * scl;                   // body
    }
}

// Kernel 2: 256-thread stream-compaction scan (wave-64 shuffle scan, 2
// barriers). Emits inverse map: colof[r] = column of r-th crossing,
// tailval[r] = val there, count = total crossings. (Verified in R3/R4.)
__global__ void scan_kernel(const float* __restrict__ val,
                            const int* __restrict__ flag,
                            int* __restrict__ colof,
                            float* __restrict__ tailval,
                            int* __restrict__ count) {
    const int t    = threadIdx.x;        // 256 threads
    const int lane = t & 63;
    const int wave = t >> 6;             // 4 waves
    const int PER  = NCOL / 256;         // 32 consecutive columns per thread

    int f[PER];
    int mysum = 0;
    const vi4* fp = (const vi4*)(flag + t * PER);
    for (int j = 0; j < PER / 4; ++j) {
        vi4 v = fp[j];
        f[4*j+0] = v.x; f[4*j+1] = v.y; f[4*j+2] = v.z; f[4*j+3] = v.w;
        mysum += v.x + v.y + v.z + v.w;
    }

    int s = mysum;
    for (int off = 1; off < 64; off <<= 1) {
        int v = __shfl_up(s, off);
        if (lane >= off) s += v;
    }

    __shared__ int wsum[4];
    if (lane == 63) wsum[wave] = s;
    __syncthreads();
    int wbase = 0;
    for (int w = 0; w < wave; ++w) wbase += wsum[w];

    int running = wbase + s - mysum;     // exclusive prefix for this thread

    for (int j = 0; j < PER; ++j) {
        int k = t * PER + j;
        if (f[j]) {
            colof[running]   = k;
            tailval[running] = val[k];
            ++running;
        }
    }
    if (t == 255) *count = wsum[0] + wsum[1] + wsum[2] + wsum[3];
}

// Kernel 3: scatter the (at most NCOL) nonzero tail values onto the zeroed
// tail. Row r gets tailval[r] at column colof[r]. Stream order guarantees
// the zeros land first.
__global__ void diag_kernel(const int* __restrict__ colof,
                            const float* __restrict__ tailval,
                            const int* __restrict__ count,
                            float* __restrict__ out) {
    int r = blockIdx.x * blockDim.x + threadIdx.x;
    int cnt = *count;
    if (r < cnt)
        out[TAIL_OFF + (size_t)r * NCOL + colof[r]] = tailval[r];
}

extern "C" void kernel_launch(void* const* d_in, const int* in_sizes, int n_in,
                              void* d_out, int out_size, void* d_ws, size_t ws_size,
                              hipStream_t stream) {
    const float* x = (const float*)d_in[0];
    float* out = (float*)d_out;

    fused_kernel<<<STAT_BLOCKS + FILL_BLOCKS, 256, 0, stream>>>(
        x, out, WS_VAL(d_ws), WS_FLAG(d_ws));
    scan_kernel<<<1, 256, 0, stream>>>(WS_VAL(d_ws), WS_FLAG(d_ws),
                                       WS_COLOF(d_ws), WS_TAILVAL(d_ws), WS_COUNT(d_ws));
    diag_kernel<<<NCOL / 256, 256, 0, stream>>>(WS_COLOF(d_ws), WS_TAILVAL(d_ws),
                                                WS_COUNT(d_ws), out);
}